// Round 1
// 542.996 us; speedup vs baseline: 1.3617x; 1.3617x over previous
//
#include <hip/hip_runtime.h>
#include <hip/hip_bf16.h>

// Problem constants (B=2, S=2048, D=2048, H=16, dk=128)
#define SEQ   2048
#define DIM   2048
#define NH    16
#define DKH   128
#define BATCH 2
#define MROWS (BATCH * SEQ)   // 4096
#define NQT   (SEQ / 64)      // 32 q-tiles per (b,h)

using bf16 = __hip_bfloat16;
typedef __attribute__((ext_vector_type(8))) short short8;
typedef __attribute__((ext_vector_type(4))) short short4v;
typedef __attribute__((ext_vector_type(4))) float floatx4;

union BfBits { bf16 h; short s; };

// async global->LDS, 16 bytes per lane (wave-uniform LDS base + lane*16)
__device__ __forceinline__ void gl_lds16(const bf16* g, bf16* l) {
  __builtin_amdgcn_global_load_lds(
      (__attribute__((address_space(1))) void*)(g),
      (__attribute__((address_space(3))) void*)(l), 16, 0, 0);
}

// ---------------- cast fp32 -> bf16 (4 elems / thread) ----------------
__global__ __launch_bounds__(256) void cast_kernel(const float* __restrict__ src,
                                                   bf16* __restrict__ dst, int n4) {
  int i = blockIdx.x * 256 + threadIdx.x;
  if (i >= n4) return;
  float4 v = reinterpret_cast<const float4*>(src)[i];
  __hip_bfloat162 h01, h23;
  h01.x = __float2bfloat16(v.x); h01.y = __float2bfloat16(v.y);
  h23.x = __float2bfloat16(v.z); h23.y = __float2bfloat16(v.w);
  reinterpret_cast<__hip_bfloat162*>(dst)[i * 2 + 0] = h01;
  reinterpret_cast<__hip_bfloat162*>(dst)[i * 2 + 1] = h23;
}

// ---------------- bf16 MFMA GEMM (m97 structure): C(MxN) = A(MxK) @ Bw(NxK)^T ----
// 128x128 tile, BK=32, linear [128][32] LDS staged via global_load_lds width=16.
template <typename CT>
__global__ __launch_bounds__(256) void gemm_bt(const bf16* __restrict__ A,
                                               const bf16* __restrict__ Bw,
                                               CT* __restrict__ C,
                                               int M, int N, int K) {
  __shared__ bf16 As[128 * 32];
  __shared__ bf16 Bs[128 * 32];
  const int t = threadIdx.x;
  const int m0 = blockIdx.y * 128;
  const int n0 = blockIdx.x * 128;
  const int w = t >> 6, lane = t & 63;
  const int wm = (w >> 1) * 64, wn = (w & 1) * 64;
  const int lr = lane & 15, quad = lane >> 4;

  // staging geometry: tile = 128x32 bf16 = 8 KB = 8 chunks of 1024 B.
  // wave w stages chunks {2w, 2w+1}. Within a chunk, lane l covers
  // row = chunk*16 + (l>>2), col = (l&3)*8  (16 B per lane, linear in LDS).
  const int c0 = w * 2;
  const int r0 = lane >> 2;
  const int kc = (lane & 3) * 8;

  floatx4 acc[4][4];
#pragma unroll
  for (int i = 0; i < 4; ++i)
#pragma unroll
    for (int j = 0; j < 4; ++j)
      acc[i][j] = (floatx4){0.f, 0.f, 0.f, 0.f};

  for (int k0 = 0; k0 < K; k0 += 32) {
    gl_lds16(A + (size_t)(m0 + c0 * 16 + r0) * K + k0 + kc,       As + c0 * 512);
    gl_lds16(A + (size_t)(m0 + (c0 + 1) * 16 + r0) * K + k0 + kc, As + (c0 + 1) * 512);
    gl_lds16(Bw + (size_t)(n0 + c0 * 16 + r0) * K + k0 + kc,       Bs + c0 * 512);
    gl_lds16(Bw + (size_t)(n0 + (c0 + 1) * 16 + r0) * K + k0 + kc, Bs + (c0 + 1) * 512);
    __syncthreads();

    short8 af[4], bfr[4];
#pragma unroll
    for (int i = 0; i < 4; ++i)
      af[i] = *reinterpret_cast<const short8*>(As + (wm + i * 16 + lr) * 32 + quad * 8);
#pragma unroll
    for (int j = 0; j < 4; ++j)
      bfr[j] = *reinterpret_cast<const short8*>(Bs + (wn + j * 16 + lr) * 32 + quad * 8);
#pragma unroll
    for (int i = 0; i < 4; ++i)
#pragma unroll
      for (int j = 0; j < 4; ++j)
        acc[i][j] = __builtin_amdgcn_mfma_f32_16x16x32_bf16(af[i], bfr[j], acc[i][j], 0, 0, 0);
    __syncthreads();
  }

#pragma unroll
  for (int i = 0; i < 4; ++i)
#pragma unroll
    for (int j = 0; j < 4; ++j) {
      int mrow = m0 + wm + i * 16 + quad * 4;
      int ncol = n0 + wn + j * 16 + lr;
#pragma unroll
      for (int rr = 0; rr < 4; ++rr) {
        if constexpr (__is_same(CT, float))
          C[(size_t)(mrow + rr) * N + ncol] = acc[i][j][rr];
        else
          C[(size_t)(mrow + rr) * N + ncol] = __float2bfloat16(acc[i][j][rr]);
      }
    }
}

// ---------------- RoPE Q: bf16 (B,S,D) -> bf16 (B,H,S,dk) ----------------
__global__ __launch_bounds__(256) void rope_q(const bf16* __restrict__ Qraw,
                                              const float* __restrict__ cosT,
                                              const float* __restrict__ sinT,
                                              bf16* __restrict__ Qb) {
  int g = blockIdx.x * 256 + threadIdx.x;  // pair index, < M*D/2
  int p = g & 63;
  int r = g >> 6;                 // (b*S+s)*16 + h
  int h = r & 15;
  int s = (r >> 4) & (SEQ - 1);
  int b = r >> 15;
  __hip_bfloat162 v = reinterpret_cast<const __hip_bfloat162*>(Qraw)[g];
  float x0 = __bfloat162float(v.x), x1 = __bfloat162float(v.y);
  float c = cosT[s * 64 + p], sn = sinT[s * 64 + p];
  __hip_bfloat162 o;
  o.x = __float2bfloat16(x0 * c - x1 * sn);
  o.y = __float2bfloat16(x0 * sn + x1 * c);
  reinterpret_cast<__hip_bfloat162*>(Qb)[((size_t)(b * NH + h) * SEQ + s) * 64 + p] = o;
}

// ---------------- RoPE K: fp32 (B,S,D) in-place + bf16 (B,H,S,dk) ----------------
__global__ __launch_bounds__(256) void rope_k(float* __restrict__ Kf,
                                              const float* __restrict__ cosT,
                                              const float* __restrict__ sinT,
                                              bf16* __restrict__ Kb) {
  int g = blockIdx.x * 256 + threadIdx.x;
  int p = g & 63;
  int r = g >> 6;
  int h = r & 15;
  int s = (r >> 4) & (SEQ - 1);
  int b = r >> 15;
  float2 v = reinterpret_cast<const float2*>(Kf)[g];
  float c = cosT[s * 64 + p], sn = sinT[s * 64 + p];
  float o0 = v.x * c - v.y * sn;
  float o1 = v.x * sn + v.y * c;
  reinterpret_cast<float2*>(Kf)[g] = make_float2(o0, o1);
  __hip_bfloat162 ob;
  ob.x = __float2bfloat16(o0);
  ob.y = __float2bfloat16(o1);
  reinterpret_cast<__hip_bfloat162*>(Kb)[((size_t)(b * NH + h) * SEQ + s) * 64 + p] = ob;
}

// ---------------- V transpose: fp32 (B,S,D) -> bf16 (B,H,dk,S) ----------------
__global__ __launch_bounds__(256) void vt_kernel(const float* __restrict__ V,
                                                 bf16* __restrict__ Vt) {
  __shared__ float tile[32][33];
  const int s0 = blockIdx.x * 32;
  const int d0 = blockIdx.y * 32;
  const int bh = blockIdx.z;
  const int b = bh >> 4, h = bh & 15;
  const int t = threadIdx.x;
  const int row = t >> 3, c4 = (t & 7) * 4;

  float4 v = *reinterpret_cast<const float4*>(
      V + (size_t)(b * SEQ + s0 + row) * DIM + h * DKH + d0 + c4);
  tile[row][c4 + 0] = v.x; tile[row][c4 + 1] = v.y;
  tile[row][c4 + 2] = v.z; tile[row][c4 + 3] = v.w;
  __syncthreads();

  short4v ov;
#pragma unroll
  for (int i = 0; i < 4; ++i) {
    BfBits u; u.h = __float2bfloat16(tile[c4 + i][row]);
    ov[i] = u.s;
  }
  *reinterpret_cast<short4v*>(Vt + ((size_t)(b * NH + h) * DKH + d0 + row) * SEQ + s0 + c4) = ov;
}

// ---------------- MFMA flash attention, paired q-tiles for causal balance ------
// Block: 256 thr = 4 waves, one (b,h). Block bx processes q-tiles
// {NQT-1-bx, bx} sequentially -> every block does exactly NQT+1 = 33 KV-tile
// iterations (uniform work; fixes 6% occupancy of the 1-tile-per-block version).
// Grid: 16 x 16 x 2 = 512 blocks = 2 blocks/CU, all co-resident.
__global__ __launch_bounds__(256) void attn_mfma(const bf16* __restrict__ Qb,
                                                 const bf16* __restrict__ Kb,
                                                 const bf16* __restrict__ Vt,
                                                 bf16* __restrict__ ctx) {
  const int bx = blockIdx.x;  // 0..NQT/2-1
  const int h = blockIdx.y;
  const int b = blockIdx.z;
  const int t = threadIdx.x;
  const int w = t >> 6, lane = t & 63;
  const int lr = lane & 15, quad = lane >> 4;

  __shared__ short Ks[64 * 136];   // K tile rows padded 128->136
  __shared__ short Vs[128 * 72];   // Vt tile rows padded 64->72
  __shared__ short Ps[4 * 16 * 72];  // per-wave P strips

  const float scale = 0.08838834764831845f;  // 1/sqrt(128)
  const size_t headQK = (size_t)(b * NH + h) * SEQ * DKH;

  for (int pass = 0; pass < 2; ++pass) {
    const int qt = pass ? bx : (NQT - 1 - bx);

    // Q fragments for this wave's 16-row strip (resident across all kt)
    short8 qa[4];
    {
      const short* qbase = (const short*)Qb + headQK + (size_t)(qt * 64 + w * 16 + lr) * DKH;
#pragma unroll
      for (int kk = 0; kk < 4; ++kk)
        qa[kk] = *reinterpret_cast<const short8*>(qbase + kk * 32 + quad * 8);
    }

    floatx4 o[8];
#pragma unroll
    for (int n = 0; n < 8; ++n) o[n] = (floatx4){0.f, 0.f, 0.f, 0.f};
    float m[4] = {-1e30f, -1e30f, -1e30f, -1e30f};
    float l[4] = {0.f, 0.f, 0.f, 0.f};

    for (int kt = 0; kt <= qt; ++kt) {
      // stage K tile (contiguous 16 KB in global)
      {
        const short* kbase = (const short*)Kb + headQK + (size_t)(kt * 64) * DKH;
#pragma unroll
        for (int u = 0; u < 4; ++u) {
          int c = t + 256 * u;
          *reinterpret_cast<int4*>(Ks + (c >> 4) * 136 + (c & 15) * 8) =
              *reinterpret_cast<const int4*>(kbase + c * 8);
        }
        const short* vbase = (const short*)Vt + (size_t)(b * NH + h) * DKH * SEQ + kt * 64;
#pragma unroll
        for (int u = 0; u < 4; ++u) {
          int c = t + 256 * u;
          *reinterpret_cast<int4*>(Vs + (c >> 3) * 72 + (c & 7) * 8) =
              *reinterpret_cast<const int4*>(vbase + (size_t)(c >> 3) * SEQ + (c & 7) * 8);
        }
      }
      __syncthreads();

      // QK^T: S strip 16x64 for this wave
      floatx4 sj[4];
#pragma unroll
      for (int j = 0; j < 4; ++j) sj[j] = (floatx4){0.f, 0.f, 0.f, 0.f};
#pragma unroll
      for (int j = 0; j < 4; ++j)
#pragma unroll
        for (int kk = 0; kk < 4; ++kk) {
          short8 kb = *reinterpret_cast<const short8*>(Ks + (j * 16 + lr) * 136 + kk * 32 + quad * 8);
          sj[j] = __builtin_amdgcn_mfma_f32_16x16x32_bf16(qa[kk], kb, sj[j], 0, 0, 0);
        }

      // scale + causal mask (diagonal tile only)
      float sc[4][4];
#pragma unroll
      for (int j = 0; j < 4; ++j)
#pragma unroll
        for (int r = 0; r < 4; ++r) sc[j][r] = sj[j][r] * scale;
      if (kt == qt) {
#pragma unroll
        for (int j = 0; j < 4; ++j) {
          int col = kt * 64 + j * 16 + lr;
#pragma unroll
          for (int r = 0; r < 4; ++r) {
            int rowg = qt * 64 + w * 16 + quad * 4 + r;
            if (col > rowg) sc[j][r] = -1e9f;
          }
        }
      }

      // online softmax, per row r (row = quad*4+r; cols across lr + j*16)
#pragma unroll
      for (int r = 0; r < 4; ++r) {
        float mx = fmaxf(fmaxf(sc[0][r], sc[1][r]), fmaxf(sc[2][r], sc[3][r]));
        mx = fmaxf(mx, __shfl_xor(mx, 1, 16));
        mx = fmaxf(mx, __shfl_xor(mx, 2, 16));
        mx = fmaxf(mx, __shfl_xor(mx, 4, 16));
        mx = fmaxf(mx, __shfl_xor(mx, 8, 16));
        float mnew = fmaxf(m[r], mx);
        float alpha = __expf(m[r] - mnew);
        float rs = 0.f;
#pragma unroll
        for (int j = 0; j < 4; ++j) {
          float p = __expf(sc[j][r] - mnew);
          rs += p;
          BfBits u; u.h = __float2bfloat16(p);
          Ps[(w * 16 + quad * 4 + r) * 72 + j * 16 + lr] = u.s;
        }
        rs += __shfl_xor(rs, 1, 16);
        rs += __shfl_xor(rs, 2, 16);
        rs += __shfl_xor(rs, 4, 16);
        rs += __shfl_xor(rs, 8, 16);
        l[r] = l[r] * alpha + rs;
        m[r] = mnew;
#pragma unroll
        for (int n = 0; n < 8; ++n) o[n][r] *= alpha;
      }

      // PV: wave-private P strip (no barrier needed; wave LDS ops are ordered)
      short8 pa0 = *reinterpret_cast<const short8*>(Ps + (w * 16 + lr) * 72 + quad * 8);
      short8 pa1 = *reinterpret_cast<const short8*>(Ps + (w * 16 + lr) * 72 + 32 + quad * 8);
#pragma unroll
      for (int n = 0; n < 8; ++n) {
        short8 vb0 = *reinterpret_cast<const short8*>(Vs + (n * 16 + lr) * 72 + quad * 8);
        short8 vb1 = *reinterpret_cast<const short8*>(Vs + (n * 16 + lr) * 72 + 32 + quad * 8);
        o[n] = __builtin_amdgcn_mfma_f32_16x16x32_bf16(pa0, vb0, o[n], 0, 0, 0);
        o[n] = __builtin_amdgcn_mfma_f32_16x16x32_bf16(pa1, vb1, o[n], 0, 0, 0);
      }
      __syncthreads();
    }

    // epilogue: normalize, store ctx (B,S,D) bf16
    float inv[4];
#pragma unroll
    for (int r = 0; r < 4; ++r) inv[r] = 1.0f / l[r];
#pragma unroll
    for (int r = 0; r < 4; ++r) {
      size_t mrow = (size_t)b * SEQ + qt * 64 + w * 16 + quad * 4 + r;
      bf16* dst = ctx + mrow * DIM + h * DKH;
#pragma unroll
      for (int n = 0; n < 8; ++n)
        dst[n * 16 + lr] = __float2bfloat16(o[n][r] * inv[r]);
    }
    // safe to re-stage LDS next pass: last kt iteration ended with __syncthreads
    // and the epilogue touches only registers/global.
  }
}

// ---------------- launch ----------------
extern "C" void kernel_launch(void* const* d_in, const int* in_sizes, int n_in,
                              void* d_out, int out_size, void* d_ws, size_t ws_size,
                              hipStream_t stream) {
  const float* x = (const float*)d_in[0];
  const float* fcos = (const float*)d_in[1];
  const float* fsin = (const float*)d_in[2];
  // d_in[3] = mask (causal applied analytically)
  const float* Wq = (const float*)d_in[4];
  const float* Wk = (const float*)d_in[5];
  const float* Wv = (const float*)d_in[6];
  const float* Wo = (const float*)d_in[7];

  float* out = (float*)d_out;                  // M x D
  float* Kout = out + (size_t)MROWS * DIM;     // K cache (fp32, post-RoPE)
  float* Vout = Kout + (size_t)MROWS * DIM;    // V cache (fp32)

  // workspace layout (~117 MB)
  const size_t MD = (size_t)MROWS * DIM;       // 8.39M
  const size_t DD = (size_t)DIM * DIM;         // 4.19M
  bf16* xb   = (bf16*)d_ws;          // MD
  bf16* Wqb  = xb + MD;              // DD x4
  bf16* Wkb  = Wqb + DD;
  bf16* Wvb  = Wkb + DD;
  bf16* Wob  = Wvb + DD;
  bf16* Qraw = Wob + DD;             // MD  (pre-RoPE Q, (B,S,D)); reused as ctxb
  bf16* Qb   = Qraw + MD;            // MD  (post-RoPE, (B,H,S,dk))
  bf16* Kb   = Qb + MD;              // MD  (post-RoPE, (B,H,S,dk))
  bf16* Vt   = Kb + MD;              // MD  ((B,H,dk,S))
  bf16* ctxb = Qraw;                 // alias: Qraw dead after rope_q

  const int nXD4 = MROWS * DIM / 4;
  const int nWD4 = DIM * DIM / 4;
  cast_kernel<<<nXD4 / 256, 256, 0, stream>>>(x, xb, nXD4);
  cast_kernel<<<nWD4 / 256, 256, 0, stream>>>(Wq, Wqb, nWD4);
  cast_kernel<<<nWD4 / 256, 256, 0, stream>>>(Wk, Wkb, nWD4);
  cast_kernel<<<nWD4 / 256, 256, 0, stream>>>(Wv, Wvb, nWD4);
  cast_kernel<<<nWD4 / 256, 256, 0, stream>>>(Wo, Wob, nWD4);

  dim3 gg(DIM / 128, MROWS / 128);  // (16, 32)
  gemm_bt<bf16><<<gg, 256, 0, stream>>>(xb, Wqb, Qraw, MROWS, DIM, DIM);
  gemm_bt<float><<<gg, 256, 0, stream>>>(xb, Wkb, Kout, MROWS, DIM, DIM);
  gemm_bt<float><<<gg, 256, 0, stream>>>(xb, Wvb, Vout, MROWS, DIM, DIM);

  const int npairs = MROWS * DIM / 2;  // 4,194,304
  rope_q<<<npairs / 256, 256, 0, stream>>>(Qraw, fcos, fsin, Qb);
  rope_k<<<npairs / 256, 256, 0, stream>>>(Kout, fcos, fsin, Kb);

  dim3 gv(SEQ / 32, DKH / 32, BATCH * NH);  // (64, 4, 32)
  vt_kernel<<<gv, 256, 0, stream>>>(Vout, Vt);

  dim3 ga(NQT / 2, NH, BATCH);  // (16, 16, 2) — paired q-tiles, uniform 33 iters
  attn_mfma<<<ga, 256, 0, stream>>>(Qb, Kb, Vt, ctxb);

  gemm_bt<float><<<gg, 256, 0, stream>>>(ctxb, Wob, out, MROWS, DIM, DIM);
}

// Round 2
// 520.174 us; speedup vs baseline: 1.4214x; 1.0439x over previous
//
#include <hip/hip_runtime.h>
#include <hip/hip_bf16.h>

// Problem constants (B=2, S=2048, D=2048, H=16, dk=128)
#define SEQ   2048
#define DIM   2048
#define NH    16
#define DKH   128
#define BATCH 2
#define MROWS (BATCH * SEQ)   // 4096
#define NQT   (SEQ / 64)      // 32 q-tiles per (b,h)

using bf16 = __hip_bfloat16;
typedef __attribute__((ext_vector_type(8))) short short8;
typedef __attribute__((ext_vector_type(4))) short short4v;
typedef __attribute__((ext_vector_type(4))) float floatx4;

union BfBits { bf16 h; short s; };

// async global->LDS, 16 bytes per lane (wave-uniform LDS base + lane*16)
__device__ __forceinline__ void gl_lds16(const bf16* g, bf16* l) {
  __builtin_amdgcn_global_load_lds(
      (__attribute__((address_space(1))) void*)(g),
      (__attribute__((address_space(3))) void*)(l), 16, 0, 0);
}

// ---------------- merged cast fp32 -> bf16 for x + 4 weights ----------------
// Destinations are contiguous in workspace: xb (nX4*4 bf16) then Wqb,Wkb,Wvb,Wob.
// nX4 = 2^21 float4s, each weight = 2^20 float4s.
__global__ __launch_bounds__(256) void cast5_kernel(const float* __restrict__ x,
                                                    const float* __restrict__ wq,
                                                    const float* __restrict__ wk,
                                                    const float* __restrict__ wv,
                                                    const float* __restrict__ wo,
                                                    bf16* __restrict__ dst,
                                                    int nX4, int nW4, int nTot) {
  int i = blockIdx.x * 256 + threadIdx.x;
  if (i >= nTot) return;
  const float* src;
  int off;
  int j = i - nX4;
  if (j < 0) { src = x; off = i; }
  else {
    int wsel = j >> 20;          // nW4 = 2^20
    off = j & (nW4 - 1);
    src = (wsel == 0) ? wq : (wsel == 1) ? wk : (wsel == 2) ? wv : wo;
  }
  float4 v = reinterpret_cast<const float4*>(src)[off];
  __hip_bfloat162 h01, h23;
  h01.x = __float2bfloat16(v.x); h01.y = __float2bfloat16(v.y);
  h23.x = __float2bfloat16(v.z); h23.y = __float2bfloat16(v.w);
  reinterpret_cast<__hip_bfloat162*>(dst)[i * 2 + 0] = h01;
  reinterpret_cast<__hip_bfloat162*>(dst)[i * 2 + 1] = h23;
}

// ---------------- fused QKV GEMM: C(4096 x 6144) = xb @ [Wq;Wk;Wv]^T ----------
// m97 structure: 128x128 tile, BK=32, linear [128][32] LDS via global_load_lds.
// Grid (48,32) = 1536 blocks = 6/CU. Epilogue routes by col region:
//   [0,2048) -> Qraw bf16, [2048,4096) -> Kout fp32, [4096,6144) -> Vout fp32.
__global__ __launch_bounds__(256) void gemm_qkv(const bf16* __restrict__ A,
                                                const bf16* __restrict__ Bw,
                                                bf16* __restrict__ Qraw,
                                                float* __restrict__ Kout,
                                                float* __restrict__ Vout) {
  __shared__ bf16 As[128 * 32];
  __shared__ bf16 Bs[128 * 32];
  const int t = threadIdx.x;
  const int m0 = blockIdx.y * 128;
  const int n0 = blockIdx.x * 128;
  const int w = t >> 6, lane = t & 63;
  const int wm = (w >> 1) * 64, wn = (w & 1) * 64;
  const int lr = lane & 15, quad = lane >> 4;

  const int c0 = w * 2;
  const int r0 = lane >> 2;
  const int kc = (lane & 3) * 8;

  floatx4 acc[4][4];
#pragma unroll
  for (int i = 0; i < 4; ++i)
#pragma unroll
    for (int j = 0; j < 4; ++j)
      acc[i][j] = (floatx4){0.f, 0.f, 0.f, 0.f};

  for (int k0 = 0; k0 < DIM; k0 += 32) {
    gl_lds16(A + (size_t)(m0 + c0 * 16 + r0) * DIM + k0 + kc,       As + c0 * 512);
    gl_lds16(A + (size_t)(m0 + (c0 + 1) * 16 + r0) * DIM + k0 + kc, As + (c0 + 1) * 512);
    gl_lds16(Bw + (size_t)(n0 + c0 * 16 + r0) * DIM + k0 + kc,       Bs + c0 * 512);
    gl_lds16(Bw + (size_t)(n0 + (c0 + 1) * 16 + r0) * DIM + k0 + kc, Bs + (c0 + 1) * 512);
    __syncthreads();

    short8 af[4], bfr[4];
#pragma unroll
    for (int i = 0; i < 4; ++i)
      af[i] = *reinterpret_cast<const short8*>(As + (wm + i * 16 + lr) * 32 + quad * 8);
#pragma unroll
    for (int j = 0; j < 4; ++j)
      bfr[j] = *reinterpret_cast<const short8*>(Bs + (wn + j * 16 + lr) * 32 + quad * 8);
#pragma unroll
    for (int i = 0; i < 4; ++i)
#pragma unroll
      for (int j = 0; j < 4; ++j)
        acc[i][j] = __builtin_amdgcn_mfma_f32_16x16x32_bf16(af[i], bfr[j], acc[i][j], 0, 0, 0);
    __syncthreads();
  }

  const int region = n0 >> 11;  // 0=Q, 1=K, 2=V (tiles never straddle regions)
#pragma unroll
  for (int i = 0; i < 4; ++i)
#pragma unroll
    for (int j = 0; j < 4; ++j) {
      int mrow = m0 + wm + i * 16 + quad * 4;
      int lcol = (n0 & 2047) + wn + j * 16 + lr;
#pragma unroll
      for (int rr = 0; rr < 4; ++rr) {
        size_t idx = (size_t)(mrow + rr) * DIM + lcol;
        if (region == 0)      Qraw[idx] = __float2bfloat16(acc[i][j][rr]);
        else if (region == 1) Kout[idx] = acc[i][j][rr];
        else                  Vout[idx] = acc[i][j][rr];
      }
    }
}

// ---------------- bf16 MFMA GEMM (m97 structure): C(MxN) = A(MxK) @ Bw(NxK)^T ----
template <typename CT>
__global__ __launch_bounds__(256) void gemm_bt(const bf16* __restrict__ A,
                                               const bf16* __restrict__ Bw,
                                               CT* __restrict__ C,
                                               int M, int N, int K) {
  __shared__ bf16 As[128 * 32];
  __shared__ bf16 Bs[128 * 32];
  const int t = threadIdx.x;
  const int m0 = blockIdx.y * 128;
  const int n0 = blockIdx.x * 128;
  const int w = t >> 6, lane = t & 63;
  const int wm = (w >> 1) * 64, wn = (w & 1) * 64;
  const int lr = lane & 15, quad = lane >> 4;

  const int c0 = w * 2;
  const int r0 = lane >> 2;
  const int kc = (lane & 3) * 8;

  floatx4 acc[4][4];
#pragma unroll
  for (int i = 0; i < 4; ++i)
#pragma unroll
    for (int j = 0; j < 4; ++j)
      acc[i][j] = (floatx4){0.f, 0.f, 0.f, 0.f};

  for (int k0 = 0; k0 < K; k0 += 32) {
    gl_lds16(A + (size_t)(m0 + c0 * 16 + r0) * K + k0 + kc,       As + c0 * 512);
    gl_lds16(A + (size_t)(m0 + (c0 + 1) * 16 + r0) * K + k0 + kc, As + (c0 + 1) * 512);
    gl_lds16(Bw + (size_t)(n0 + c0 * 16 + r0) * K + k0 + kc,       Bs + c0 * 512);
    gl_lds16(Bw + (size_t)(n0 + (c0 + 1) * 16 + r0) * K + k0 + kc, Bs + (c0 + 1) * 512);
    __syncthreads();

    short8 af[4], bfr[4];
#pragma unroll
    for (int i = 0; i < 4; ++i)
      af[i] = *reinterpret_cast<const short8*>(As + (wm + i * 16 + lr) * 32 + quad * 8);
#pragma unroll
    for (int j = 0; j < 4; ++j)
      bfr[j] = *reinterpret_cast<const short8*>(Bs + (wn + j * 16 + lr) * 32 + quad * 8);
#pragma unroll
    for (int i = 0; i < 4; ++i)
#pragma unroll
      for (int j = 0; j < 4; ++j)
        acc[i][j] = __builtin_amdgcn_mfma_f32_16x16x32_bf16(af[i], bfr[j], acc[i][j], 0, 0, 0);
    __syncthreads();
  }

#pragma unroll
  for (int i = 0; i < 4; ++i)
#pragma unroll
    for (int j = 0; j < 4; ++j) {
      int mrow = m0 + wm + i * 16 + quad * 4;
      int ncol = n0 + wn + j * 16 + lr;
#pragma unroll
      for (int rr = 0; rr < 4; ++rr) {
        if constexpr (__is_same(CT, float))
          C[(size_t)(mrow + rr) * N + ncol] = acc[i][j][rr];
        else
          C[(size_t)(mrow + rr) * N + ncol] = __float2bfloat16(acc[i][j][rr]);
      }
    }
}

// ---------------- RoPE Q: bf16 (B,S,D) -> bf16 (B,H,S,dk) ----------------
__global__ __launch_bounds__(256) void rope_q(const bf16* __restrict__ Qraw,
                                              const float* __restrict__ cosT,
                                              const float* __restrict__ sinT,
                                              bf16* __restrict__ Qb) {
  int g = blockIdx.x * 256 + threadIdx.x;  // pair index, < M*D/2
  int p = g & 63;
  int r = g >> 6;                 // (b*S+s)*16 + h
  int h = r & 15;
  int s = (r >> 4) & (SEQ - 1);
  int b = r >> 15;
  __hip_bfloat162 v = reinterpret_cast<const __hip_bfloat162*>(Qraw)[g];
  float x0 = __bfloat162float(v.x), x1 = __bfloat162float(v.y);
  float c = cosT[s * 64 + p], sn = sinT[s * 64 + p];
  __hip_bfloat162 o;
  o.x = __float2bfloat16(x0 * c - x1 * sn);
  o.y = __float2bfloat16(x0 * sn + x1 * c);
  reinterpret_cast<__hip_bfloat162*>(Qb)[((size_t)(b * NH + h) * SEQ + s) * 64 + p] = o;
}

// ---------------- RoPE K: fp32 (B,S,D) in-place + bf16 (B,H,S,dk) ----------------
__global__ __launch_bounds__(256) void rope_k(float* __restrict__ Kf,
                                              const float* __restrict__ cosT,
                                              const float* __restrict__ sinT,
                                              bf16* __restrict__ Kb) {
  int g = blockIdx.x * 256 + threadIdx.x;
  int p = g & 63;
  int r = g >> 6;
  int h = r & 15;
  int s = (r >> 4) & (SEQ - 1);
  int b = r >> 15;
  float2 v = reinterpret_cast<const float2*>(Kf)[g];
  float c = cosT[s * 64 + p], sn = sinT[s * 64 + p];
  float o0 = v.x * c - v.y * sn;
  float o1 = v.x * sn + v.y * c;
  reinterpret_cast<float2*>(Kf)[g] = make_float2(o0, o1);
  __hip_bfloat162 ob;
  ob.x = __float2bfloat16(o0);
  ob.y = __float2bfloat16(o1);
  reinterpret_cast<__hip_bfloat162*>(Kb)[((size_t)(b * NH + h) * SEQ + s) * 64 + p] = ob;
}

// ---------------- V transpose: fp32 (B,S,D) -> bf16 (B,H,dk,S) ----------------
__global__ __launch_bounds__(256) void vt_kernel(const float* __restrict__ V,
                                                 bf16* __restrict__ Vt) {
  __shared__ float tile[32][33];
  const int s0 = blockIdx.x * 32;
  const int d0 = blockIdx.y * 32;
  const int bh = blockIdx.z;
  const int b = bh >> 4, h = bh & 15;
  const int t = threadIdx.x;
  const int row = t >> 3, c4 = (t & 7) * 4;

  float4 v = *reinterpret_cast<const float4*>(
      V + (size_t)(b * SEQ + s0 + row) * DIM + h * DKH + d0 + c4);
  tile[row][c4 + 0] = v.x; tile[row][c4 + 1] = v.y;
  tile[row][c4 + 2] = v.z; tile[row][c4 + 3] = v.w;
  __syncthreads();

  short4v ov;
#pragma unroll
  for (int i = 0; i < 4; ++i) {
    BfBits u; u.h = __float2bfloat16(tile[c4 + i][row]);
    ov[i] = u.s;
  }
  *reinterpret_cast<short4v*>(Vt + ((size_t)(b * NH + h) * DKH + d0 + row) * SEQ + s0 + c4) = ov;
}

// ---------------- MFMA flash attention, paired q-tiles for causal balance ------
// Block bx processes q-tiles {NQT-1-bx, bx}: uniform 33 KV-iters per block.
// Softmax in log2 domain (scale folded with log2e) + T13 defer-rescale.
__global__ __launch_bounds__(256) void attn_mfma(const bf16* __restrict__ Qb,
                                                 const bf16* __restrict__ Kb,
                                                 const bf16* __restrict__ Vt,
                                                 bf16* __restrict__ ctx) {
  const int bx = blockIdx.x;  // 0..NQT/2-1
  const int h = blockIdx.y;
  const int b = blockIdx.z;
  const int t = threadIdx.x;
  const int w = t >> 6, lane = t & 63;
  const int lr = lane & 15, quad = lane >> 4;

  __shared__ short Ks[64 * 136];   // K tile rows padded 128->136
  __shared__ short Vs[128 * 72];   // Vt tile rows padded 64->72
  __shared__ short Ps[4 * 16 * 72];  // per-wave P strips

  // scale * log2(e): softmax entirely in exp2 domain
  const float scale2 = 0.08838834764831845f * 1.44269504f;
  const float THR = 11.5413f;      // 8 * log2(e): defer-rescale threshold
  const size_t headQK = (size_t)(b * NH + h) * SEQ * DKH;

  for (int pass = 0; pass < 2; ++pass) {
    const int qt = pass ? bx : (NQT - 1 - bx);

    // Q fragments for this wave's 16-row strip (resident across all kt)
    short8 qa[4];
    {
      const short* qbase = (const short*)Qb + headQK + (size_t)(qt * 64 + w * 16 + lr) * DKH;
#pragma unroll
      for (int kk = 0; kk < 4; ++kk)
        qa[kk] = *reinterpret_cast<const short8*>(qbase + kk * 32 + quad * 8);
    }

    floatx4 o[8];
#pragma unroll
    for (int n = 0; n < 8; ++n) o[n] = (floatx4){0.f, 0.f, 0.f, 0.f};
    float m[4] = {-1e30f, -1e30f, -1e30f, -1e30f};
    float l[4] = {0.f, 0.f, 0.f, 0.f};

    for (int kt = 0; kt <= qt; ++kt) {
      // stage K tile (contiguous 16 KB in global)
      {
        const short* kbase = (const short*)Kb + headQK + (size_t)(kt * 64) * DKH;
#pragma unroll
        for (int u = 0; u < 4; ++u) {
          int c = t + 256 * u;
          *reinterpret_cast<int4*>(Ks + (c >> 4) * 136 + (c & 15) * 8) =
              *reinterpret_cast<const int4*>(kbase + c * 8);
        }
        const short* vbase = (const short*)Vt + (size_t)(b * NH + h) * DKH * SEQ + kt * 64;
#pragma unroll
        for (int u = 0; u < 4; ++u) {
          int c = t + 256 * u;
          *reinterpret_cast<int4*>(Vs + (c >> 3) * 72 + (c & 7) * 8) =
              *reinterpret_cast<const int4*>(vbase + (size_t)(c >> 3) * SEQ + (c & 7) * 8);
        }
      }
      __syncthreads();

      // QK^T: S strip 16x64 for this wave
      floatx4 sj[4];
#pragma unroll
      for (int j = 0; j < 4; ++j) sj[j] = (floatx4){0.f, 0.f, 0.f, 0.f};
#pragma unroll
      for (int j = 0; j < 4; ++j)
#pragma unroll
        for (int kk = 0; kk < 4; ++kk) {
          short8 kb = *reinterpret_cast<const short8*>(Ks + (j * 16 + lr) * 136 + kk * 32 + quad * 8);
          sj[j] = __builtin_amdgcn_mfma_f32_16x16x32_bf16(qa[kk], kb, sj[j], 0, 0, 0);
        }

      // scale (log2 domain) + causal mask (diagonal tile only)
      float sc[4][4];
#pragma unroll
      for (int j = 0; j < 4; ++j)
#pragma unroll
        for (int r = 0; r < 4; ++r) sc[j][r] = sj[j][r] * scale2;
      if (kt == qt) {
#pragma unroll
        for (int j = 0; j < 4; ++j) {
          int col = kt * 64 + j * 16 + lr;
#pragma unroll
          for (int r = 0; r < 4; ++r) {
            int rowg = qt * 64 + w * 16 + quad * 4 + r;
            if (col > rowg) sc[j][r] = -1e9f;
          }
        }
      }

      // online softmax, per row r (row = quad*4+r; cols across lr + j*16)
#pragma unroll
      for (int r = 0; r < 4; ++r) {
        float mx = fmaxf(fmaxf(sc[0][r], sc[1][r]), fmaxf(sc[2][r], sc[3][r]));
        mx = fmaxf(mx, __shfl_xor(mx, 1, 16));
        mx = fmaxf(mx, __shfl_xor(mx, 2, 16));
        mx = fmaxf(mx, __shfl_xor(mx, 4, 16));
        mx = fmaxf(mx, __shfl_xor(mx, 8, 16));
        // T13: only rescale when this tile's max meaningfully exceeds running m
        if (!__all(mx - m[r] <= THR)) {
          float mnew = fmaxf(m[r], mx);
          float alpha = __builtin_amdgcn_exp2f(m[r] - mnew);
          l[r] *= alpha;
#pragma unroll
          for (int n = 0; n < 8; ++n) o[n][r] *= alpha;
          m[r] = mnew;
        }
        float rs = 0.f;
#pragma unroll
        for (int j = 0; j < 4; ++j) {
          float p = __builtin_amdgcn_exp2f(sc[j][r] - m[r]);
          rs += p;
          BfBits u; u.h = __float2bfloat16(p);
          Ps[(w * 16 + quad * 4 + r) * 72 + j * 16 + lr] = u.s;
        }
        rs += __shfl_xor(rs, 1, 16);
        rs += __shfl_xor(rs, 2, 16);
        rs += __shfl_xor(rs, 4, 16);
        rs += __shfl_xor(rs, 8, 16);
        l[r] += rs;
      }

      // PV: wave-private P strip (no barrier needed; wave LDS ops are ordered)
      short8 pa0 = *reinterpret_cast<const short8*>(Ps + (w * 16 + lr) * 72 + quad * 8);
      short8 pa1 = *reinterpret_cast<const short8*>(Ps + (w * 16 + lr) * 72 + 32 + quad * 8);
#pragma unroll
      for (int n = 0; n < 8; ++n) {
        short8 vb0 = *reinterpret_cast<const short8*>(Vs + (n * 16 + lr) * 72 + quad * 8);
        short8 vb1 = *reinterpret_cast<const short8*>(Vs + (n * 16 + lr) * 72 + 32 + quad * 8);
        o[n] = __builtin_amdgcn_mfma_f32_16x16x32_bf16(pa0, vb0, o[n], 0, 0, 0);
        o[n] = __builtin_amdgcn_mfma_f32_16x16x32_bf16(pa1, vb1, o[n], 0, 0, 0);
      }
      __syncthreads();
    }

    // epilogue: normalize, store ctx (B,S,D) bf16
    float inv[4];
#pragma unroll
    for (int r = 0; r < 4; ++r) inv[r] = 1.0f / l[r];
#pragma unroll
    for (int r = 0; r < 4; ++r) {
      size_t mrow = (size_t)b * SEQ + qt * 64 + w * 16 + quad * 4 + r;
      bf16* dst = ctx + mrow * DIM + h * DKH;
#pragma unroll
      for (int n = 0; n < 8; ++n)
        dst[n * 16 + lr] = __float2bfloat16(o[n][r] * inv[r]);
    }
  }
}

// ---------------- launch ----------------
extern "C" void kernel_launch(void* const* d_in, const int* in_sizes, int n_in,
                              void* d_out, int out_size, void* d_ws, size_t ws_size,
                              hipStream_t stream) {
  const float* x = (const float*)d_in[0];
  const float* fcos = (const float*)d_in[1];
  const float* fsin = (const float*)d_in[2];
  // d_in[3] = mask (causal applied analytically)
  const float* Wq = (const float*)d_in[4];
  const float* Wk = (const float*)d_in[5];
  const float* Wv = (const float*)d_in[6];
  const float* Wo = (const float*)d_in[7];

  float* out = (float*)d_out;                  // M x D
  float* Kout = out + (size_t)MROWS * DIM;     // K cache (fp32, post-RoPE)
  float* Vout = Kout + (size_t)MROWS * DIM;    // V cache (fp32)

  // workspace layout (~117 MB)
  const size_t MD = (size_t)MROWS * DIM;       // 8.39M
  const size_t DD = (size_t)DIM * DIM;         // 4.19M
  bf16* xb   = (bf16*)d_ws;          // MD
  bf16* Wqb  = xb + MD;              // DD x4 (contiguous: fused QKV B-matrix)
  bf16* Wkb  = Wqb + DD;
  bf16* Wvb  = Wkb + DD;
  bf16* Wob  = Wvb + DD;
  bf16* Qraw = Wob + DD;             // MD  (pre-RoPE Q, (B,S,D)); reused as ctxb
  bf16* Qb   = Qraw + MD;            // MD  (post-RoPE, (B,H,S,dk))
  bf16* Kb   = Qb + MD;              // MD  (post-RoPE, (B,H,S,dk))
  bf16* Vt   = Kb + MD;              // MD  ((B,H,dk,S))
  bf16* ctxb = Qraw;                 // alias: Qraw dead after rope_q

  const int nXD4 = MROWS * DIM / 4;  // 2^21
  const int nWD4 = DIM * DIM / 4;    // 2^20
  const int nTot = nXD4 + 4 * nWD4;  // 6,291,456
  cast5_kernel<<<nTot / 256, 256, 0, stream>>>(x, Wq, Wk, Wv, Wo, xb, nXD4, nWD4, nTot);

  // fused QKV projection: one GEMM, N=6144, 1536 blocks
  dim3 gq(3 * DIM / 128, MROWS / 128);  // (48, 32)
  gemm_qkv<<<gq, 256, 0, stream>>>(xb, Wqb, Qraw, Kout, Vout);

  const int npairs = MROWS * DIM / 2;  // 4,194,304
  rope_q<<<npairs / 256, 256, 0, stream>>>(Qraw, fcos, fsin, Qb);
  rope_k<<<npairs / 256, 256, 0, stream>>>(Kout, fcos, fsin, Kb);

  dim3 gv(SEQ / 32, DKH / 32, BATCH * NH);  // (64, 4, 32)
  vt_kernel<<<gv, 256, 0, stream>>>(Vout, Vt);

  dim3 ga(NQT / 2, NH, BATCH);  // (16, 16, 2) — paired q-tiles, uniform 33 iters
  attn_mfma<<<ga, 256, 0, stream>>>(Qb, Kb, Vt, ctxb);

  dim3 gg(DIM / 128, MROWS / 128);  // (16, 32)
  gemm_bt<float><<<gg, 256, 0, stream>>>(ctxb, Wob, out, MROWS, DIM, DIM);
}

// Round 4
// 476.586 us; speedup vs baseline: 1.5514x; 1.0915x over previous
//
#include <hip/hip_runtime.h>
#include <hip/hip_bf16.h>

// Problem constants (B=2, S=2048, D=2048, H=16, dk=128)
#define SEQ   2048
#define DIM   2048
#define NH    16
#define DKH   128
#define BATCH 2
#define MROWS (BATCH * SEQ)   // 4096
#define NQT   (SEQ / 64)      // 32 q-tiles per (b,h)

using bf16 = __hip_bfloat16;
typedef __attribute__((ext_vector_type(8))) short short8;
typedef __attribute__((ext_vector_type(4))) short short4v;
typedef __attribute__((ext_vector_type(4))) float floatx4;

union BfBits { bf16 h; short s; };

// async global->LDS, 16 bytes per lane (wave-uniform LDS base + lane*16)
__device__ __forceinline__ void gl_lds16(const bf16* g, bf16* l) {
  __builtin_amdgcn_global_load_lds(
      (__attribute__((address_space(1))) void*)(g),
      (__attribute__((address_space(3))) void*)(l), 16, 0, 0);
}

#define S_BAR  __builtin_amdgcn_s_barrier()
#define VMCNT6 do { asm volatile("s_waitcnt vmcnt(6)" ::: "memory"); __builtin_amdgcn_sched_barrier(0); } while (0)
#define VMCNT0 do { asm volatile("s_waitcnt vmcnt(0)" ::: "memory"); __builtin_amdgcn_sched_barrier(0); } while (0)
#define LGKM0  do { asm volatile("s_waitcnt lgkmcnt(0)" ::: "memory"); __builtin_amdgcn_sched_barrier(0); } while (0)

// ---------------- merged cast fp32 -> bf16 for x + 4 weights ----------------
__global__ __launch_bounds__(256) void cast5_kernel(const float* __restrict__ x,
                                                    const float* __restrict__ wq,
                                                    const float* __restrict__ wk,
                                                    const float* __restrict__ wv,
                                                    const float* __restrict__ wo,
                                                    bf16* __restrict__ dst,
                                                    int nX4, int nW4, int nTot) {
  int i = blockIdx.x * 256 + threadIdx.x;
  if (i >= nTot) return;
  const float* src;
  int off;
  int j = i - nX4;
  if (j < 0) { src = x; off = i; }
  else {
    int wsel = j >> 20;          // nW4 = 2^20
    off = j & (nW4 - 1);
    src = (wsel == 0) ? wq : (wsel == 1) ? wk : (wsel == 2) ? wv : wo;
  }
  float4 v = reinterpret_cast<const float4*>(src)[off];
  __hip_bfloat162 h01, h23;
  h01.x = __float2bfloat16(v.x); h01.y = __float2bfloat16(v.y);
  h23.x = __float2bfloat16(v.z); h23.y = __float2bfloat16(v.w);
  reinterpret_cast<__hip_bfloat162*>(dst)[i * 2 + 0] = h01;
  reinterpret_cast<__hip_bfloat162*>(dst)[i * 2 + 1] = h23;
}

// ============ pipelined 256x128 GEMM, BK=64, counted vmcnt (T3+T4+T2+T5) =====
// C(M x Nt) = A(M x 2048) @ Bw(Nt x 2048)^T.  512 thr = 8 waves (2M x 4N).
// Per wave: 128 rows x 32 cols = 8x2 fragments of 16x16, K-tile = 64.
// LDS: A dbuf 2x(256x64) + B dbuf 2x(128x64) bf16 = 96 KiB -> 1 block/CU.
// Sync per K-tile: [compute 4 phases] BAR [stage kt+2] vmcnt(6) BAR.
// kt+2's loads stay in flight across kt+1's compute (T4: never vmcnt(0)).
// LDS XOR-swizzle (T2): element col ^= 8*(row&7); applied on the global
// source during staging (rule 21: gl_lds writes linearly) and on ds_read.
// MODE 0: QKV routing (cols 0-2047 -> Qraw bf16, 2048-4095 -> Kout f32,
//         4096-6143 -> Vout f32).  MODE 1: plain fp32 C via Kout (N = DIM).
template <int ROWS>
__device__ __forceinline__ void stage_swz(const bf16* __restrict__ G, bf16* lds,
                                          int row0, int k0, int w, int l) {
  const int rr = w * 8 + (l >> 3);                 // row within 64-row issue
  const int cc = ((l & 7) * 8) ^ ((l >> 3) * 8);   // pre-swizzled col (elems)
#pragma unroll
  for (int u = 0; u < ROWS / 64; ++u)
    gl_lds16(G + (size_t)(row0 + u * 64 + rr) * DIM + k0 + cc,
             lds + (u * 64 + w * 8) * 64);
}

template <int MODE>
__global__ __launch_bounds__(512, 2) void gemm256(const bf16* __restrict__ A,
                                                  const bf16* __restrict__ Bw,
                                                  bf16* __restrict__ Qraw,
                                                  float* __restrict__ Kout,
                                                  float* __restrict__ Vout) {
  __shared__ bf16 smem[2 * 256 * 64 + 2 * 128 * 64];  // LA[2] | LB[2]
  bf16* LA = smem;                 // 2 x 16384 elems
  bf16* LB = smem + 2 * 256 * 64;  // 2 x 8192 elems

  const int t = threadIdx.x;
  const int w = t >> 6, l = t & 63;
  const int lr = l & 15, quad = l >> 4;
  const int wr = w >> 2;           // 0..1 : row half (128 rows)
  const int wc = w & 3;            // 0..3 : col strip (32 cols)
  const int m0 = blockIdx.y * 256;
  const int n0g = blockIdx.x * 128;

  const int cb = ((quad * 8) ^ ((lr & 7) * 8));  // swizzled k-col base (elems)

  floatx4 acc[8][2];
#pragma unroll
  for (int mi = 0; mi < 8; ++mi)
#pragma unroll
    for (int nj = 0; nj < 2; ++nj) acc[mi][nj] = (floatx4){0.f, 0.f, 0.f, 0.f};

  const int NT = DIM / 64;  // 32 K-tiles

  // prologue: stage tiles 0 and 1 (6 gl_lds per wave each)
  stage_swz<256>(A, LA, m0, 0, w, l);
  stage_swz<128>(Bw, LB, n0g, 0, w, l);
  stage_swz<256>(A, LA + 256 * 64, m0, 64, w, l);
  stage_swz<128>(Bw, LB + 128 * 64, n0g, 64, w, l);
  VMCNT6;  // 12 outstanding -> oldest 6 (tile 0) landed
  S_BAR;

  int cur = 0;
  for (int kt = 0; kt < NT; ++kt) {
    const bf16* la = LA + cur * (256 * 64);
    const bf16* lb = LB + cur * (128 * 64);

    // B fragments once per tile (reused by all 4 phases)
    short8 bfr[2][2];
#pragma unroll
    for (int nj = 0; nj < 2; ++nj) {
      int rb = (wc * 32 + nj * 16 + lr) * 64;
      bfr[nj][0] = *reinterpret_cast<const short8*>(lb + rb + cb);
      bfr[nj][1] = *reinterpret_cast<const short8*>(lb + rb + (cb ^ 32));
    }

    // 4 phases: quarter of the wave's rows x full K=64, 16 MFMA each
#pragma unroll
    for (int qp = 0; qp < 4; ++qp) {
      short8 af[4][2];
#pragma unroll
      for (int i = 0; i < 4; ++i) {
        int ra = (wr * 128 + (qp * 4 + i) * 16 + lr) * 64;
        af[i][0] = *reinterpret_cast<const short8*>(la + ra + cb);
        af[i][1] = *reinterpret_cast<const short8*>(la + ra + (cb ^ 32));
      }
      LGKM0;
      __builtin_amdgcn_s_setprio(1);
#pragma unroll
      for (int i = 0; i < 4; ++i)
#pragma unroll
        for (int nj = 0; nj < 2; ++nj) {
          acc[qp * 4 + i][nj] = __builtin_amdgcn_mfma_f32_16x16x32_bf16(
              af[i][0], bfr[nj][0], acc[qp * 4 + i][nj], 0, 0, 0);
          acc[qp * 4 + i][nj] = __builtin_amdgcn_mfma_f32_16x16x32_bf16(
              af[i][1], bfr[nj][1], acc[qp * 4 + i][nj], 0, 0, 0);
        }
      __builtin_amdgcn_s_setprio(0);
    }

    S_BAR;  // all waves done reading buf[cur] (lgkm drained per-phase)
    if (kt + 2 < NT) {
      stage_swz<256>(A, LA + cur * (256 * 64), m0, (kt + 2) * 64, w, l);
      stage_swz<128>(Bw, LB + cur * (128 * 64), n0g, (kt + 2) * 64, w, l);
      VMCNT6;  // kt+1's 6 loads retired; kt+2's may stay in flight
    } else {
      VMCNT0;  // drain tail
    }
    S_BAR;     // buf[cur^1] published to all waves
    cur ^= 1;
  }

  // epilogue
#pragma unroll
  for (int mi = 0; mi < 8; ++mi)
#pragma unroll
    for (int nj = 0; nj < 2; ++nj) {
      int rg = m0 + wr * 128 + mi * 16 + quad * 4;
      if constexpr (MODE == 0) {
        const int region = n0g >> 11;
        int lcol = (n0g & 2047) + wc * 32 + nj * 16 + lr;
#pragma unroll
        for (int rr2 = 0; rr2 < 4; ++rr2) {
          size_t idx = (size_t)(rg + rr2) * DIM + lcol;
          if (region == 0)      Qraw[idx] = __float2bfloat16(acc[mi][nj][rr2]);
          else if (region == 1) Kout[idx] = acc[mi][nj][rr2];
          else                  Vout[idx] = acc[mi][nj][rr2];
        }
      } else {
        int lcol = n0g + wc * 32 + nj * 16 + lr;
#pragma unroll
        for (int rr2 = 0; rr2 < 4; ++rr2)
          Kout[(size_t)(rg + rr2) * DIM + lcol] = acc[mi][nj][rr2];
      }
    }
}

// ---------------- RoPE Q: bf16 (B,S,D) -> bf16 (B,H,S,dk) ----------------
__global__ __launch_bounds__(256) void rope_q(const bf16* __restrict__ Qraw,
                                              const float* __restrict__ cosT,
                                              const float* __restrict__ sinT,
                                              bf16* __restrict__ Qb) {
  int g = blockIdx.x * 256 + threadIdx.x;  // pair index, < M*D/2
  int p = g & 63;
  int r = g >> 6;                 // (b*S+s)*16 + h
  int h = r & 15;
  int s = (r >> 4) & (SEQ - 1);
  int b = r >> 15;
  __hip_bfloat162 v = reinterpret_cast<const __hip_bfloat162*>(Qraw)[g];
  float x0 = __bfloat162float(v.x), x1 = __bfloat162float(v.y);
  float c = cosT[s * 64 + p], sn = sinT[s * 64 + p];
  __hip_bfloat162 o;
  o.x = __float2bfloat16(x0 * c - x1 * sn);
  o.y = __float2bfloat16(x0 * sn + x1 * c);
  reinterpret_cast<__hip_bfloat162*>(Qb)[((size_t)(b * NH + h) * SEQ + s) * 64 + p] = o;
}

// ---------------- RoPE K: fp32 (B,S,D) in-place + bf16 (B,H,S,dk) ----------------
__global__ __launch_bounds__(256) void rope_k(float* __restrict__ Kf,
                                              const float* __restrict__ cosT,
                                              const float* __restrict__ sinT,
                                              bf16* __restrict__ Kb) {
  int g = blockIdx.x * 256 + threadIdx.x;
  int p = g & 63;
  int r = g >> 6;
  int h = r & 15;
  int s = (r >> 4) & (SEQ - 1);
  int b = r >> 15;
  float2 v = reinterpret_cast<const float2*>(Kf)[g];
  float c = cosT[s * 64 + p], sn = sinT[s * 64 + p];
  float o0 = v.x * c - v.y * sn;
  float o1 = v.x * sn + v.y * c;
  reinterpret_cast<float2*>(Kf)[g] = make_float2(o0, o1);
  __hip_bfloat162 ob;
  ob.x = __float2bfloat16(o0);
  ob.y = __float2bfloat16(o1);
  reinterpret_cast<__hip_bfloat162*>(Kb)[((size_t)(b * NH + h) * SEQ + s) * 64 + p] = ob;
}

// ---------------- V transpose: fp32 (B,S,D) -> bf16 (B,H,dk,S) ----------------
__global__ __launch_bounds__(256) void vt_kernel(const float* __restrict__ V,
                                                 bf16* __restrict__ Vt) {
  __shared__ float tile[32][33];
  const int s0 = blockIdx.x * 32;
  const int d0 = blockIdx.y * 32;
  const int bh = blockIdx.z;
  const int b = bh >> 4, h = bh & 15;
  const int t = threadIdx.x;
  const int row = t >> 3, c4 = (t & 7) * 4;

  float4 v = *reinterpret_cast<const float4*>(
      V + (size_t)(b * SEQ + s0 + row) * DIM + h * DKH + d0 + c4);
  tile[row][c4 + 0] = v.x; tile[row][c4 + 1] = v.y;
  tile[row][c4 + 2] = v.z; tile[row][c4 + 3] = v.w;
  __syncthreads();

  short4v ov;
#pragma unroll
  for (int i = 0; i < 4; ++i) {
    BfBits u; u.h = __float2bfloat16(tile[c4 + i][row]);
    ov[i] = u.s;
  }
  *reinterpret_cast<short4v*>(Vt + ((size_t)(b * NH + h) * DKH + d0 + row) * SEQ + s0 + c4) = ov;
}

// ---------------- MFMA flash attention, paired q-tiles for causal balance ------
__global__ __launch_bounds__(256) void attn_mfma(const bf16* __restrict__ Qb,
                                                 const bf16* __restrict__ Kb,
                                                 const bf16* __restrict__ Vt,
                                                 bf16* __restrict__ ctx) {
  const int bx = blockIdx.x;  // 0..NQT/2-1
  const int h = blockIdx.y;
  const int b = blockIdx.z;
  const int t = threadIdx.x;
  const int w = t >> 6, lane = t & 63;
  const int lr = lane & 15, quad = lane >> 4;

  __shared__ short Ks[64 * 136];   // K tile rows padded 128->136
  __shared__ short Vs[128 * 72];   // Vt tile rows padded 64->72
  __shared__ short Ps[4 * 16 * 72];  // per-wave P strips

  const float scale2 = 0.08838834764831845f * 1.44269504f;  // 1/sqrt(128)*log2e
  const float THR = 11.5413f;      // 8 * log2(e): defer-rescale threshold
  const size_t headQK = (size_t)(b * NH + h) * SEQ * DKH;

  for (int pass = 0; pass < 2; ++pass) {
    const int qt = pass ? bx : (NQT - 1 - bx);

    short8 qa[4];
    {
      const short* qbase = (const short*)Qb + headQK + (size_t)(qt * 64 + w * 16 + lr) * DKH;
#pragma unroll
      for (int kk = 0; kk < 4; ++kk)
        qa[kk] = *reinterpret_cast<const short8*>(qbase + kk * 32 + quad * 8);
    }

    floatx4 o[8];
#pragma unroll
    for (int n = 0; n < 8; ++n) o[n] = (floatx4){0.f, 0.f, 0.f, 0.f};
    float m[4] = {-1e30f, -1e30f, -1e30f, -1e30f};
    float l[4] = {0.f, 0.f, 0.f, 0.f};

    for (int kt = 0; kt <= qt; ++kt) {
      {
        const short* kbase = (const short*)Kb + headQK + (size_t)(kt * 64) * DKH;
#pragma unroll
        for (int u = 0; u < 4; ++u) {
          int c = t + 256 * u;
          *reinterpret_cast<int4*>(Ks + (c >> 4) * 136 + (c & 15) * 8) =
              *reinterpret_cast<const int4*>(kbase + c * 8);
        }
        const short* vbase = (const short*)Vt + (size_t)(b * NH + h) * DKH * SEQ + kt * 64;
#pragma unroll
        for (int u = 0; u < 4; ++u) {
          int c = t + 256 * u;
          *reinterpret_cast<int4*>(Vs + (c >> 3) * 72 + (c & 7) * 8) =
              *reinterpret_cast<const int4*>(vbase + (size_t)(c >> 3) * SEQ + (c & 7) * 8);
        }
      }
      __syncthreads();

      floatx4 sj[4];
#pragma unroll
      for (int j = 0; j < 4; ++j) sj[j] = (floatx4){0.f, 0.f, 0.f, 0.f};
#pragma unroll
      for (int j = 0; j < 4; ++j)
#pragma unroll
        for (int kk = 0; kk < 4; ++kk) {
          short8 kb = *reinterpret_cast<const short8*>(Ks + (j * 16 + lr) * 136 + kk * 32 + quad * 8);
          sj[j] = __builtin_amdgcn_mfma_f32_16x16x32_bf16(qa[kk], kb, sj[j], 0, 0, 0);
        }

      float sc[4][4];
#pragma unroll
      for (int j = 0; j < 4; ++j)
#pragma unroll
        for (int r = 0; r < 4; ++r) sc[j][r] = sj[j][r] * scale2;
      if (kt == qt) {
#pragma unroll
        for (int j = 0; j < 4; ++j) {
          int col = kt * 64 + j * 16 + lr;
#pragma unroll
          for (int r = 0; r < 4; ++r) {
            int rowg = qt * 64 + w * 16 + quad * 4 + r;
            if (col > rowg) sc[j][r] = -1e9f;
          }
        }
      }

#pragma unroll
      for (int r = 0; r < 4; ++r) {
        float mx = fmaxf(fmaxf(sc[0][r], sc[1][r]), fmaxf(sc[2][r], sc[3][r]));
        mx = fmaxf(mx, __shfl_xor(mx, 1, 16));
        mx = fmaxf(mx, __shfl_xor(mx, 2, 16));
        mx = fmaxf(mx, __shfl_xor(mx, 4, 16));
        mx = fmaxf(mx, __shfl_xor(mx, 8, 16));
        if (!__all(mx - m[r] <= THR)) {
          float mnew = fmaxf(m[r], mx);
          float alpha = __builtin_amdgcn_exp2f(m[r] - mnew);
          l[r] *= alpha;
#pragma unroll
          for (int n = 0; n < 8; ++n) o[n][r] *= alpha;
          m[r] = mnew;
        }
        float rs = 0.f;
#pragma unroll
        for (int j = 0; j < 4; ++j) {
          float p = __builtin_amdgcn_exp2f(sc[j][r] - m[r]);
          rs += p;
          BfBits u; u.h = __float2bfloat16(p);
          Ps[(w * 16 + quad * 4 + r) * 72 + j * 16 + lr] = u.s;
        }
        rs += __shfl_xor(rs, 1, 16);
        rs += __shfl_xor(rs, 2, 16);
        rs += __shfl_xor(rs, 4, 16);
        rs += __shfl_xor(rs, 8, 16);
        l[r] += rs;
      }

      short8 pa0 = *reinterpret_cast<const short8*>(Ps + (w * 16 + lr) * 72 + quad * 8);
      short8 pa1 = *reinterpret_cast<const short8*>(Ps + (w * 16 + lr) * 72 + 32 + quad * 8);
#pragma unroll
      for (int n = 0; n < 8; ++n) {
        short8 vb0 = *reinterpret_cast<const short8*>(Vs + (n * 16 + lr) * 72 + quad * 8);
        short8 vb1 = *reinterpret_cast<const short8*>(Vs + (n * 16 + lr) * 72 + 32 + quad * 8);
        o[n] = __builtin_amdgcn_mfma_f32_16x16x32_bf16(pa0, vb0, o[n], 0, 0, 0);
        o[n] = __builtin_amdgcn_mfma_f32_16x16x32_bf16(pa1, vb1, o[n], 0, 0, 0);
      }
      __syncthreads();
    }

    float inv[4];
#pragma unroll
    for (int r = 0; r < 4; ++r) inv[r] = 1.0f / l[r];
#pragma unroll
    for (int r = 0; r < 4; ++r) {
      size_t mrow = (size_t)b * SEQ + qt * 64 + w * 16 + quad * 4 + r;
      bf16* dst = ctx + mrow * DIM + h * DKH;
#pragma unroll
      for (int n = 0; n < 8; ++n)
        dst[n * 16 + lr] = __float2bfloat16(o[n][r] * inv[r]);
    }
  }
}

// ---------------- launch ----------------
extern "C" void kernel_launch(void* const* d_in, const int* in_sizes, int n_in,
                              void* d_out, int out_size, void* d_ws, size_t ws_size,
                              hipStream_t stream) {
  const float* x = (const float*)d_in[0];
  const float* fcos = (const float*)d_in[1];
  const float* fsin = (const float*)d_in[2];
  // d_in[3] = mask (causal applied analytically)
  const float* Wq = (const float*)d_in[4];
  const float* Wk = (const float*)d_in[5];
  const float* Wv = (const float*)d_in[6];
  const float* Wo = (const float*)d_in[7];

  float* out = (float*)d_out;                  // M x D
  float* Kout = out + (size_t)MROWS * DIM;     // K cache (fp32, post-RoPE)
  float* Vout = Kout + (size_t)MROWS * DIM;    // V cache (fp32)

  const size_t MD = (size_t)MROWS * DIM;       // 8.39M
  const size_t DD = (size_t)DIM * DIM;         // 4.19M
  bf16* xb   = (bf16*)d_ws;          // MD
  bf16* Wqb  = xb + MD;              // DD x4 (contiguous: fused QKV B-matrix)
  bf16* Wkb  = Wqb + DD;
  bf16* Wvb  = Wkb + DD;
  bf16* Wob  = Wvb + DD;
  bf16* Qraw = Wob + DD;             // MD  (pre-RoPE Q, (B,S,D)); reused as ctxb
  bf16* Qb   = Qraw + MD;            // MD  (post-RoPE, (B,H,S,dk))
  bf16* Kb   = Qb + MD;              // MD  (post-RoPE, (B,H,S,dk))
  bf16* Vt   = Kb + MD;              // MD  ((B,H,dk,S))
  bf16* ctxb = Qraw;                 // alias: Qraw dead after rope_q

  const int nXD4 = MROWS * DIM / 4;  // 2^21
  const int nWD4 = DIM * DIM / 4;    // 2^20
  const int nTot = nXD4 + 4 * nWD4;  // 6,291,456
  cast5_kernel<<<nTot / 256, 256, 0, stream>>>(x, Wq, Wk, Wv, Wo, xb, nXD4, nWD4, nTot);

  // fused QKV projection: 256x128 pipelined tiles, grid 48x16 = 768 = 3/CU
  dim3 gq(3 * DIM / 128, MROWS / 256);
  gemm256<0><<<gq, 512, 0, stream>>>(xb, Wqb, Qraw, Kout, Vout);

  const int npairs = MROWS * DIM / 2;  // 4,194,304
  rope_q<<<npairs / 256, 256, 0, stream>>>(Qraw, fcos, fsin, Qb);
  rope_k<<<npairs / 256, 256, 0, stream>>>(Kout, fcos, fsin, Kb);

  dim3 gv(SEQ / 32, DKH / 32, BATCH * NH);  // (64, 4, 32)
  vt_kernel<<<gv, 256, 0, stream>>>(Vout, Vt);

  dim3 ga(NQT / 2, NH, BATCH);  // (16, 16, 2) — paired q-tiles, uniform 33 iters
  attn_mfma<<<ga, 256, 0, stream>>>(Qb, Kb, Vt, ctxb);

  // output projection: grid 16x16 = 256 = 1/CU
  dim3 go(DIM / 128, MROWS / 256);
  gemm256<1><<<go, 512, 0, stream>>>(ctxb, Wob, (bf16*)nullptr, out, (float*)nullptr);
}

// Round 5
// 468.712 us; speedup vs baseline: 1.5775x; 1.0168x over previous
//
#include <hip/hip_runtime.h>
#include <hip/hip_bf16.h>

// Problem constants (B=2, S=2048, D=2048, H=16, dk=128)
#define SEQ   2048
#define DIM   2048
#define NH    16
#define DKH   128
#define BATCH 2
#define MROWS (BATCH * SEQ)   // 4096
#define NQT   (SEQ / 64)      // 32 q-tiles per (b,h)

using bf16 = __hip_bfloat16;
typedef __attribute__((ext_vector_type(8))) short short8;
typedef __attribute__((ext_vector_type(4))) short short4v;
typedef __attribute__((ext_vector_type(4))) float floatx4;

union BfBits { bf16 h; short s; };

// async global->LDS, 16 bytes per lane (wave-uniform LDS base + lane*16)
__device__ __forceinline__ void gl_lds16(const bf16* g, bf16* l) {
  __builtin_amdgcn_global_load_lds(
      (__attribute__((address_space(1))) void*)(g),
      (__attribute__((address_space(3))) void*)(l), 16, 0, 0);
}

#define S_BAR  __builtin_amdgcn_s_barrier()
#define VMCNT6 do { asm volatile("s_waitcnt vmcnt(6)" ::: "memory"); __builtin_amdgcn_sched_barrier(0); } while (0)
#define VMCNT0 do { asm volatile("s_waitcnt vmcnt(0)" ::: "memory"); __builtin_amdgcn_sched_barrier(0); } while (0)
#define LGKM0  do { asm volatile("s_waitcnt lgkmcnt(0)" ::: "memory"); __builtin_amdgcn_sched_barrier(0); } while (0)

// ---------------- merged cast fp32 -> bf16 for x + 4 weights ----------------
__global__ __launch_bounds__(256) void cast5_kernel(const float* __restrict__ x,
                                                    const float* __restrict__ wq,
                                                    const float* __restrict__ wk,
                                                    const float* __restrict__ wv,
                                                    const float* __restrict__ wo,
                                                    bf16* __restrict__ dst,
                                                    int nX4, int nW4, int nTot) {
  int i = blockIdx.x * 256 + threadIdx.x;
  if (i >= nTot) return;
  const float* src;
  int off;
  int j = i - nX4;
  if (j < 0) { src = x; off = i; }
  else {
    int wsel = j >> 20;          // nW4 = 2^20
    off = j & (nW4 - 1);
    src = (wsel == 0) ? wq : (wsel == 1) ? wk : (wsel == 2) ? wv : wo;
  }
  float4 v = reinterpret_cast<const float4*>(src)[off];
  __hip_bfloat162 h01, h23;
  h01.x = __float2bfloat16(v.x); h01.y = __float2bfloat16(v.y);
  h23.x = __float2bfloat16(v.z); h23.y = __float2bfloat16(v.w);
  reinterpret_cast<__hip_bfloat162*>(dst)[i * 2 + 0] = h01;
  reinterpret_cast<__hip_bfloat162*>(dst)[i * 2 + 1] = h23;
}

// ============ pipelined 256x128 GEMM, BK=64, 3-buffer, phase-interleaved =====
// C(M x Nt) = A(M x 2048) @ Bw(Nt x 2048)^T.  512 thr = 8 waves (2M x 4N).
// Per wave: 128 rows x 32 cols = 8x2 fragments of 16x16, K-tile = 64.
// LDS: 3 buffers x (A 256x64 + B 128x64) bf16 = 144 KiB -> 1 block/CU.
// Schedule per K-tile kt (ONE barrier per tile):
//   phase A: ds_read B-frags(4) + A-frags mi0-3 (8) | issue A-stage kt+2 (4 gl)
//            lgkm0 | setprio1 | 16 MFMA | setprio0
//   phase B: ds_read A-frags mi4-7 (8)              | issue B-stage kt+2 (2 gl)
//            lgkm0 | setprio1 | 16 MFMA | setprio0
//   vmcnt(6) [kt+1's 6 loads retired; kt+2's in flight] | s_barrier
// buf[(kt+2)%3] was fully consumed at end of tile kt-1 -> safe to overwrite
// during tile kt (all waves past that barrier).  T2 XOR-swizzle as before
// (pre-swizzled global source, swizzled ds_read; verified R4, conflicts=0).
// MODE 0: QKV routing. MODE 1: plain fp32 C via Kout (N = DIM).
#define BUFE (256 * 64 + 128 * 64)   // 24576 elems per buffer

template <int ROWS>
__device__ __forceinline__ void stage_swz(const bf16* __restrict__ G, bf16* lds,
                                          int row0, int k0, int w, int l) {
  const int rr = w * 8 + (l >> 3);                 // row within 64-row issue
  const int cc = ((l & 7) * 8) ^ ((l >> 3) * 8);   // pre-swizzled col (elems)
#pragma unroll
  for (int u = 0; u < ROWS / 64; ++u)
    gl_lds16(G + (size_t)(row0 + u * 64 + rr) * DIM + k0 + cc,
             lds + (u * 64 + w * 8) * 64);
}

template <int MODE>
__global__ __launch_bounds__(512, 2) void gemm256(const bf16* __restrict__ A,
                                                  const bf16* __restrict__ Bw,
                                                  bf16* __restrict__ Qraw,
                                                  float* __restrict__ Kout,
                                                  float* __restrict__ Vout) {
  __shared__ bf16 smem[3 * BUFE];  // [buf] { A 256x64 | B 128x64 }

  const int t = threadIdx.x;
  const int w = t >> 6, l = t & 63;
  const int lr = l & 15, quad = l >> 4;
  const int wr = w >> 2;           // 0..1 : row half (128 rows)
  const int wc = w & 3;            // 0..3 : col strip (32 cols)
  const int m0 = blockIdx.y * 256;
  const int n0g = blockIdx.x * 128;

  const int cb = ((quad * 8) ^ ((lr & 7) * 8));  // swizzled k-col base (elems)

  floatx4 acc[8][2];
#pragma unroll
  for (int mi = 0; mi < 8; ++mi)
#pragma unroll
    for (int nj = 0; nj < 2; ++nj) acc[mi][nj] = (floatx4){0.f, 0.f, 0.f, 0.f};

  const int NT = DIM / 64;  // 32 K-tiles

  // prologue: stage tiles 0 and 1 (6 gl_lds per wave each)
  stage_swz<256>(A, smem, m0, 0, w, l);
  stage_swz<128>(Bw, smem + 256 * 64, n0g, 0, w, l);
  stage_swz<256>(A, smem + BUFE, m0, 64, w, l);
  stage_swz<128>(Bw, smem + BUFE + 256 * 64, n0g, 64, w, l);
  VMCNT6;  // 12 outstanding -> oldest 6 (tile 0) landed
  S_BAR;

  for (int kt = 0; kt < NT; ++kt) {
    const bf16* la = smem + (kt % 3) * BUFE;
    const bf16* lb = la + 256 * 64;
    bf16* stg = smem + ((kt + 2) % 3) * BUFE;
    const bool do_stage = (kt + 2 < NT);

    // ---- phase A: B-frags + A-frags mi 0..3 ----
    short8 bfr[2][2];
#pragma unroll
    for (int nj = 0; nj < 2; ++nj) {
      int rb = (wc * 32 + nj * 16 + lr) * 64;
      bfr[nj][0] = *reinterpret_cast<const short8*>(lb + rb + cb);
      bfr[nj][1] = *reinterpret_cast<const short8*>(lb + rb + (cb ^ 32));
    }
    short8 af[4][2];
#pragma unroll
    for (int i = 0; i < 4; ++i) {
      int ra = (wr * 128 + i * 16 + lr) * 64;
      af[i][0] = *reinterpret_cast<const short8*>(la + ra + cb);
      af[i][1] = *reinterpret_cast<const short8*>(la + ra + (cb ^ 32));
    }
    if (do_stage) stage_swz<256>(A, stg, m0, (kt + 2) * 64, w, l);  // 4 gl_lds
    LGKM0;
    __builtin_amdgcn_s_setprio(1);
#pragma unroll
    for (int i = 0; i < 4; ++i)
#pragma unroll
      for (int nj = 0; nj < 2; ++nj) {
        acc[i][nj] = __builtin_amdgcn_mfma_f32_16x16x32_bf16(
            af[i][0], bfr[nj][0], acc[i][nj], 0, 0, 0);
        acc[i][nj] = __builtin_amdgcn_mfma_f32_16x16x32_bf16(
            af[i][1], bfr[nj][1], acc[i][nj], 0, 0, 0);
      }
    __builtin_amdgcn_s_setprio(0);

    // ---- phase B: A-frags mi 4..7 ----
#pragma unroll
    for (int i = 0; i < 4; ++i) {
      int ra = (wr * 128 + (i + 4) * 16 + lr) * 64;
      af[i][0] = *reinterpret_cast<const short8*>(la + ra + cb);
      af[i][1] = *reinterpret_cast<const short8*>(la + ra + (cb ^ 32));
    }
    if (do_stage) stage_swz<128>(Bw, stg + 256 * 64, n0g, (kt + 2) * 64, w, l);  // 2 gl_lds
    LGKM0;
    __builtin_amdgcn_s_setprio(1);
#pragma unroll
    for (int i = 0; i < 4; ++i)
#pragma unroll
      for (int nj = 0; nj < 2; ++nj) {
        acc[i + 4][nj] = __builtin_amdgcn_mfma_f32_16x16x32_bf16(
            af[i][0], bfr[nj][0], acc[i + 4][nj], 0, 0, 0);
        acc[i + 4][nj] = __builtin_amdgcn_mfma_f32_16x16x32_bf16(
            af[i][1], bfr[nj][1], acc[i + 4][nj], 0, 0, 0);
      }
    __builtin_amdgcn_s_setprio(0);

    // ---- tile end: publish buf[kt+1] ----
    if (do_stage) { VMCNT6; } else { VMCNT0; }
    S_BAR;
  }

  // epilogue
#pragma unroll
  for (int mi = 0; mi < 8; ++mi)
#pragma unroll
    for (int nj = 0; nj < 2; ++nj) {
      int rg = m0 + wr * 128 + mi * 16 + quad * 4;
      if constexpr (MODE == 0) {
        const int region = n0g >> 11;
        int lcol = (n0g & 2047) + wc * 32 + nj * 16 + lr;
#pragma unroll
        for (int rr2 = 0; rr2 < 4; ++rr2) {
          size_t idx = (size_t)(rg + rr2) * DIM + lcol;
          if (region == 0)      Qraw[idx] = __float2bfloat16(acc[mi][nj][rr2]);
          else if (region == 1) Kout[idx] = acc[mi][nj][rr2];
          else                  Vout[idx] = acc[mi][nj][rr2];
        }
      } else {
        int lcol = n0g + wc * 32 + nj * 16 + lr;
#pragma unroll
        for (int rr2 = 0; rr2 < 4; ++rr2)
          Kout[(size_t)(rg + rr2) * DIM + lcol] = acc[mi][nj][rr2];
      }
    }
}

// ---------------- RoPE Q: bf16 (B,S,D) -> bf16 (B,H,S,dk) ----------------
__global__ __launch_bounds__(256) void rope_q(const bf16* __restrict__ Qraw,
                                              const float* __restrict__ cosT,
                                              const float* __restrict__ sinT,
                                              bf16* __restrict__ Qb) {
  int g = blockIdx.x * 256 + threadIdx.x;  // pair index, < M*D/2
  int p = g & 63;
  int r = g >> 6;                 // (b*S+s)*16 + h
  int h = r & 15;
  int s = (r >> 4) & (SEQ - 1);
  int b = r >> 15;
  __hip_bfloat162 v = reinterpret_cast<const __hip_bfloat162*>(Qraw)[g];
  float x0 = __bfloat162float(v.x), x1 = __bfloat162float(v.y);
  float c = cosT[s * 64 + p], sn = sinT[s * 64 + p];
  __hip_bfloat162 o;
  o.x = __float2bfloat16(x0 * c - x1 * sn);
  o.y = __float2bfloat16(x0 * sn + x1 * c);
  reinterpret_cast<__hip_bfloat162*>(Qb)[((size_t)(b * NH + h) * SEQ + s) * 64 + p] = o;
}

// ---------------- RoPE K: fp32 (B,S,D) in-place + bf16 (B,H,S,dk) ----------------
__global__ __launch_bounds__(256) void rope_k(float* __restrict__ Kf,
                                              const float* __restrict__ cosT,
                                              const float* __restrict__ sinT,
                                              bf16* __restrict__ Kb) {
  int g = blockIdx.x * 256 + threadIdx.x;
  int p = g & 63;
  int r = g >> 6;
  int h = r & 15;
  int s = (r >> 4) & (SEQ - 1);
  int b = r >> 15;
  float2 v = reinterpret_cast<const float2*>(Kf)[g];
  float c = cosT[s * 64 + p], sn = sinT[s * 64 + p];
  float o0 = v.x * c - v.y * sn;
  float o1 = v.x * sn + v.y * c;
  reinterpret_cast<float2*>(Kf)[g] = make_float2(o0, o1);
  __hip_bfloat162 ob;
  ob.x = __float2bfloat16(o0);
  ob.y = __float2bfloat16(o1);
  reinterpret_cast<__hip_bfloat162*>(Kb)[((size_t)(b * NH + h) * SEQ + s) * 64 + p] = ob;
}

// ---------------- V transpose: fp32 (B,S,D) -> bf16 (B,H,dk,S) ----------------
__global__ __launch_bounds__(256) void vt_kernel(const float* __restrict__ V,
                                                 bf16* __restrict__ Vt) {
  __shared__ float tile[32][33];
  const int s0 = blockIdx.x * 32;
  const int d0 = blockIdx.y * 32;
  const int bh = blockIdx.z;
  const int b = bh >> 4, h = bh & 15;
  const int t = threadIdx.x;
  const int row = t >> 3, c4 = (t & 7) * 4;

  float4 v = *reinterpret_cast<const float4*>(
      V + (size_t)(b * SEQ + s0 + row) * DIM + h * DKH + d0 + c4);
  tile[row][c4 + 0] = v.x; tile[row][c4 + 1] = v.y;
  tile[row][c4 + 2] = v.z; tile[row][c4 + 3] = v.w;
  __syncthreads();

  short4v ov;
#pragma unroll
  for (int i = 0; i < 4; ++i) {
    BfBits u; u.h = __float2bfloat16(tile[c4 + i][row]);
    ov[i] = u.s;
  }
  *reinterpret_cast<short4v*>(Vt + ((size_t)(b * NH + h) * DKH + d0 + row) * SEQ + s0 + c4) = ov;
}

// ---------------- MFMA flash attention, paired q-tiles for causal balance ------
__global__ __launch_bounds__(256) void attn_mfma(const bf16* __restrict__ Qb,
                                                 const bf16* __restrict__ Kb,
                                                 const bf16* __restrict__ Vt,
                                                 bf16* __restrict__ ctx) {
  const int bx = blockIdx.x;  // 0..NQT/2-1
  const int h = blockIdx.y;
  const int b = blockIdx.z;
  const int t = threadIdx.x;
  const int w = t >> 6, lane = t & 63;
  const int lr = lane & 15, quad = lane >> 4;

  __shared__ short Ks[64 * 136];   // K tile rows padded 128->136
  __shared__ short Vs[128 * 72];   // Vt tile rows padded 64->72
  __shared__ short Ps[4 * 16 * 72];  // per-wave P strips

  const float scale2 = 0.08838834764831845f * 1.44269504f;  // 1/sqrt(128)*log2e
  const float THR = 11.5413f;      // 8 * log2(e): defer-rescale threshold
  const size_t headQK = (size_t)(b * NH + h) * SEQ * DKH;

  for (int pass = 0; pass < 2; ++pass) {
    const int qt = pass ? bx : (NQT - 1 - bx);

    short8 qa[4];
    {
      const short* qbase = (const short*)Qb + headQK + (size_t)(qt * 64 + w * 16 + lr) * DKH;
#pragma unroll
      for (int kk = 0; kk < 4; ++kk)
        qa[kk] = *reinterpret_cast<const short8*>(qbase + kk * 32 + quad * 8);
    }

    floatx4 o[8];
#pragma unroll
    for (int n = 0; n < 8; ++n) o[n] = (floatx4){0.f, 0.f, 0.f, 0.f};
    float m[4] = {-1e30f, -1e30f, -1e30f, -1e30f};
    float l[4] = {0.f, 0.f, 0.f, 0.f};

    for (int kt = 0; kt <= qt; ++kt) {
      {
        const short* kbase = (const short*)Kb + headQK + (size_t)(kt * 64) * DKH;
#pragma unroll
        for (int u = 0; u < 4; ++u) {
          int c = t + 256 * u;
          *reinterpret_cast<int4*>(Ks + (c >> 4) * 136 + (c & 15) * 8) =
              *reinterpret_cast<const int4*>(kbase + c * 8);
        }
        const short* vbase = (const short*)Vt + (size_t)(b * NH + h) * DKH * SEQ + kt * 64;
#pragma unroll
        for (int u = 0; u < 4; ++u) {
          int c = t + 256 * u;
          *reinterpret_cast<int4*>(Vs + (c >> 3) * 72 + (c & 7) * 8) =
              *reinterpret_cast<const int4*>(vbase + (size_t)(c >> 3) * SEQ + (c & 7) * 8);
        }
      }
      __syncthreads();

      floatx4 sj[4];
#pragma unroll
      for (int j = 0; j < 4; ++j) sj[j] = (floatx4){0.f, 0.f, 0.f, 0.f};
#pragma unroll
      for (int j = 0; j < 4; ++j)
#pragma unroll
        for (int kk = 0; kk < 4; ++kk) {
          short8 kb = *reinterpret_cast<const short8*>(Ks + (j * 16 + lr) * 136 + kk * 32 + quad * 8);
          sj[j] = __builtin_amdgcn_mfma_f32_16x16x32_bf16(qa[kk], kb, sj[j], 0, 0, 0);
        }

      float sc[4][4];
#pragma unroll
      for (int j = 0; j < 4; ++j)
#pragma unroll
        for (int r = 0; r < 4; ++r) sc[j][r] = sj[j][r] * scale2;
      if (kt == qt) {
#pragma unroll
        for (int j = 0; j < 4; ++j) {
          int col = kt * 64 + j * 16 + lr;
#pragma unroll
          for (int r = 0; r < 4; ++r) {
            int rowg = qt * 64 + w * 16 + quad * 4 + r;
            if (col > rowg) sc[j][r] = -1e9f;
          }
        }
      }

#pragma unroll
      for (int r = 0; r < 4; ++r) {
        float mx = fmaxf(fmaxf(sc[0][r], sc[1][r]), fmaxf(sc[2][r], sc[3][r]));
        mx = fmaxf(mx, __shfl_xor(mx, 1, 16));
        mx = fmaxf(mx, __shfl_xor(mx, 2, 16));
        mx = fmaxf(mx, __shfl_xor(mx, 4, 16));
        mx = fmaxf(mx, __shfl_xor(mx, 8, 16));
        if (!__all(mx - m[r] <= THR)) {
          float mnew = fmaxf(m[r], mx);
          float alpha = __builtin_amdgcn_exp2f(m[r] - mnew);
          l[r] *= alpha;
#pragma unroll
          for (int n = 0; n < 8; ++n) o[n][r] *= alpha;
          m[r] = mnew;
        }
        float rs = 0.f;
#pragma unroll
        for (int j = 0; j < 4; ++j) {
          float p = __builtin_amdgcn_exp2f(sc[j][r] - m[r]);
          rs += p;
          BfBits u; u.h = __float2bfloat16(p);
          Ps[(w * 16 + quad * 4 + r) * 72 + j * 16 + lr] = u.s;
        }
        rs += __shfl_xor(rs, 1, 16);
        rs += __shfl_xor(rs, 2, 16);
        rs += __shfl_xor(rs, 4, 16);
        rs += __shfl_xor(rs, 8, 16);
        l[r] += rs;
      }

      short8 pa0 = *reinterpret_cast<const short8*>(Ps + (w * 16 + lr) * 72 + quad * 8);
      short8 pa1 = *reinterpret_cast<const short8*>(Ps + (w * 16 + lr) * 72 + 32 + quad * 8);
#pragma unroll
      for (int n = 0; n < 8; ++n) {
        short8 vb0 = *reinterpret_cast<const short8*>(Vs + (n * 16 + lr) * 72 + quad * 8);
        short8 vb1 = *reinterpret_cast<const short8*>(Vs + (n * 16 + lr) * 72 + 32 + quad * 8);
        o[n] = __builtin_amdgcn_mfma_f32_16x16x32_bf16(pa0, vb0, o[n], 0, 0, 0);
        o[n] = __builtin_amdgcn_mfma_f32_16x16x32_bf16(pa1, vb1, o[n], 0, 0, 0);
      }
      __syncthreads();
    }

    float inv[4];
#pragma unroll
    for (int r = 0; r < 4; ++r) inv[r] = 1.0f / l[r];
#pragma unroll
    for (int r = 0; r < 4; ++r) {
      size_t mrow = (size_t)b * SEQ + qt * 64 + w * 16 + quad * 4 + r;
      bf16* dst = ctx + mrow * DIM + h * DKH;
#pragma unroll
      for (int n = 0; n < 8; ++n)
        dst[n * 16 + lr] = __float2bfloat16(o[n][r] * inv[r]);
    }
  }
}

// ---------------- launch ----------------
extern "C" void kernel_launch(void* const* d_in, const int* in_sizes, int n_in,
                              void* d_out, int out_size, void* d_ws, size_t ws_size,
                              hipStream_t stream) {
  const float* x = (const float*)d_in[0];
  const float* fcos = (const float*)d_in[1];
  const float* fsin = (const float*)d_in[2];
  // d_in[3] = mask (causal applied analytically)
  const float* Wq = (const float*)d_in[4];
  const float* Wk = (const float*)d_in[5];
  const float* Wv = (const float*)d_in[6];
  const float* Wo = (const float*)d_in[7];

  float* out = (float*)d_out;                  // M x D
  float* Kout = out + (size_t)MROWS * DIM;     // K cache (fp32, post-RoPE)
  float* Vout = Kout + (size_t)MROWS * DIM;    // V cache (fp32)

  const size_t MD = (size_t)MROWS * DIM;       // 8.39M
  const size_t DD = (size_t)DIM * DIM;         // 4.19M
  bf16* xb   = (bf16*)d_ws;          // MD
  bf16* Wqb  = xb + MD;              // DD x4 (contiguous: fused QKV B-matrix)
  bf16* Wkb  = Wqb + DD;
  bf16* Wvb  = Wkb + DD;
  bf16* Wob  = Wvb + DD;
  bf16* Qraw = Wob + DD;             // MD  (pre-RoPE Q, (B,S,D)); reused as ctxb
  bf16* Qb   = Qraw + MD;            // MD  (post-RoPE, (B,H,S,dk))
  bf16* Kb   = Qb + MD;              // MD  (post-RoPE, (B,H,S,dk))
  bf16* Vt   = Kb + MD;              // MD  ((B,H,dk,S))
  bf16* ctxb = Qraw;                 // alias: Qraw dead after rope_q

  const int nXD4 = MROWS * DIM / 4;  // 2^21
  const int nWD4 = DIM * DIM / 4;    // 2^20
  const int nTot = nXD4 + 4 * nWD4;  // 6,291,456
  cast5_kernel<<<nTot / 256, 256, 0, stream>>>(x, Wq, Wk, Wv, Wo, xb, nXD4, nWD4, nTot);

  // fused QKV projection: 256x128 pipelined tiles, grid 48x16 = 768 = 3/CU
  dim3 gq(3 * DIM / 128, MROWS / 256);
  gemm256<0><<<gq, 512, 0, stream>>>(xb, Wqb, Qraw, Kout, Vout);

  const int npairs = MROWS * DIM / 2;  // 4,194,304
  rope_q<<<npairs / 256, 256, 0, stream>>>(Qraw, fcos, fsin, Qb);
  rope_k<<<npairs / 256, 256, 0, stream>>>(Kout, fcos, fsin, Kb);

  dim3 gv(SEQ / 32, DKH / 32, BATCH * NH);  // (64, 4, 32)
  vt_kernel<<<gv, 256, 0, stream>>>(Vout, Vt);

  dim3 ga(NQT / 2, NH, BATCH);  // (16, 16, 2) — paired q-tiles, uniform 33 iters
  attn_mfma<<<ga, 256, 0, stream>>>(Qb, Kb, Vt, ctxb);

  // output projection: grid 16x16 = 256 = 1/CU
  dim3 go(DIM / 128, MROWS / 256);
  gemm256<1><<<go, 512, 0, stream>>>(ctxb, Wob, (bf16*)nullptr, out, (float*)nullptr);
}